// Round 6
// baseline (1057.728 us; speedup 1.0000x reference)
//
#include <hip/hip_runtime.h>
#include <hip/hip_bf16.h>

#define T_TOKENS 65536
#define D_DIM 256
#define H_DIM 1024
#define E_NUM 8
#define MT 256
#define HC 32
#define NCHUNK 32              // H_DIM / HC
#define GTB 64                 // gate tokens per block

typedef __attribute__((ext_vector_type(4))) float f32x4;
typedef __attribute__((ext_vector_type(8))) short s16x8;
typedef __attribute__((ext_vector_type(4))) unsigned int u32x4;
typedef __attribute__((ext_vector_type(4))) unsigned short u16x4;
typedef __attribute__((address_space(3))) unsigned int lds_u32;
typedef const __attribute__((address_space(1))) unsigned int glb_u32;

#define MFMA __builtin_amdgcn_mfma_f32_16x16x32_bf16

__device__ __forceinline__ unsigned short f2bf(float f){
  union { float f; unsigned u; } v; v.f = f;
  unsigned r = v.u + 0x7FFFu + ((v.u >> 16) & 1u);
  return (unsigned short)(r >> 16);
}
__device__ __forceinline__ float bf2f(unsigned short h){
  return __uint_as_float((unsigned)h << 16);
}
__device__ __forceinline__ unsigned cvtpk(float lo, float hi){
  unsigned r;
  asm("v_cvt_pk_bf16_f32 %0, %1, %2" : "=v"(r) : "v"(lo), "v"(hi));
  return r;
}
__device__ __forceinline__ unsigned long long pack4(f32x4 v){
  return (unsigned long long)f2bf(v.x)
       | ((unsigned long long)f2bf(v.y) << 16)
       | ((unsigned long long)f2bf(v.z) << 32)
       | ((unsigned long long)f2bf(v.w) << 48);
}

// one 4-float unit of weight conversion into the swizzled chunk image.
// chunk(e,c) = 32KB: [W1c: 32 h-rows x 256 d, row 512B, swz (h&7)<<4]
//  + [W2p at +16384: 256 d-rows x 32 h-slots, row 64B, slot s=qj*8+mi*4+j
//     holding W2[d][mi*16+qj*4+j], swz ((d>>1)&3)<<4]
__device__ __forceinline__ void cvt_unit(int i, const float* __restrict__ W1,
                                         const float* __restrict__ W2,
                                         char* __restrict__ wsw){
  const int N1 = (E_NUM * H_DIM * D_DIM) / 4;      // 524288
  unsigned long long pk;
  size_t off;
  if (i < N1){
    pk = pack4(((const f32x4*)W1)[i]);
    int idx = i << 2;
    int e  = idx >> 18;
    int h  = (idx >> 8) & (H_DIM - 1);
    int d0 = idx & (D_DIM - 1);
    int c = h >> 5, r = h & 31;
    off = ((size_t)(e * NCHUNK + c) << 15)
        + (size_t)(((r << 9) + (d0 << 1)) ^ ((r & 7) << 4));
  } else {
    pk = pack4(((const f32x4*)W2)[i - N1]);
    int idx = (i - N1) << 2;
    int e  = idx >> 18;
    int d  = (idx >> 10) & (D_DIM - 1);
    int h0 = idx & (H_DIM - 1);
    int c  = h0 >> 5;
    int mi = (h0 >> 4) & 1, qjs = (h0 >> 2) & 3;
    int s2 = qjs * 16 + mi * 8;                    // byte offset of the 8B slot group
    off = ((size_t)(e * NCHUNK + c) << 15) + 16384
        + (size_t)((d << 6) + (s2 ^ (((d >> 1) & 3) << 4)));
  }
  *(unsigned long long*)(wsw + off) = pk;
}

// ---- gate (+fused weight conversion): scores, top-2, softmax, routing ----
__global__ __launch_bounds__(256) void gate_kernel(
    const float* __restrict__ x, const float* __restrict__ Wg,
    const float* __restrict__ bg,
    const float* __restrict__ W1, const float* __restrict__ W2,
    char* __restrict__ wsw,
    int* __restrict__ counts, int* __restrict__ tok_ids, float* __restrict__ rrec)
{
  __shared__ int lcnt[E_NUM];
  __shared__ int lbase[E_NUM];
  __shared__ unsigned char aexp[GTB * 2];
  __shared__ short         apos[GTB * 2];

  int tid = threadIdx.x, wave = tid >> 6, lane = tid & 63;

  // fused weight conversion: 4 units per thread
  int gthr = blockIdx.x * 256 + tid;
#pragma unroll
  for (int j = 0; j < 4; ++j)
    cvt_unit(gthr + j * ((T_TOKENS / GTB) * 256), W1, W2, wsw);

  if (tid < E_NUM) lcnt[tid] = 0;
  __syncthreads();

  int t0 = blockIdx.x * GTB;
#pragma unroll 1
  for (int i = 0; i < GTB / 4; ++i){
    int tl = wave * (GTB / 4) + i;
    int t = t0 + tl;
    f32x4 xv = *(const f32x4*)(x + (size_t)t * D_DIM + 4*lane);
    float s[E_NUM];
#pragma unroll
    for (int e = 0; e < E_NUM; ++e){
      f32x4 w = *(const f32x4*)(Wg + e*D_DIM + 4*lane);
      s[e] = xv.x*w.x + xv.y*w.y + xv.z*w.z + xv.w*w.w;
    }
#pragma unroll
    for (int off = 32; off; off >>= 1){
#pragma unroll
      for (int e = 0; e < E_NUM; ++e) s[e] += __shfl_xor(s[e], off);
    }
#pragma unroll
    for (int e = 0; e < E_NUM; ++e) s[e] += bg[e];
    int e0 = 0; float v0 = s[0];
#pragma unroll
    for (int e = 1; e < E_NUM; ++e) if (s[e] > v0){ v0 = s[e]; e0 = e; }
    int e1 = -1; float v1 = -3.4e38f;
#pragma unroll
    for (int e = 0; e < E_NUM; ++e){
      if (e == e0) continue;
      if (s[e] > v1){ v1 = s[e]; e1 = e; }
    }
    float ex = __expf(v1 - v0);
    float inv = 1.f / (1.f + ex);
    float p0 = inv, p1 = ex * inv;
    if (lane == 0){
      int li = tl * 2;
      int pos0 = atomicAdd(&lcnt[e0], 1);
      int pos1 = atomicAdd(&lcnt[e1], 1);
      aexp[li]   = (unsigned char)e0; apos[li]   = (short)pos0;
      aexp[li+1] = (unsigned char)e1; apos[li+1] = (short)pos1;
      f32x4 rr; rr.x = p0; rr.y = p1; rr.z = (float)e0; rr.w = (float)e1;
      *(f32x4*)(rrec + (size_t)t * 4) = rr;
    }
  }
  __syncthreads();
  if (tid < E_NUM) lbase[tid] = atomicAdd(counts + tid*16, lcnt[tid]);
  __syncthreads();
  if (tid < GTB * 2){
    int t = t0 + (tid >> 1);
    int e = aexp[tid];
    int idx = lbase[e] + apos[tid];
    tok_ids[e*T_TOKENS + idx] = t | ((tid & 1) << 16);   // token | which-bit
  }
}

// ---- grouped FFN: 256 tokens/block, 8 waves x 32 tokens, h in registers,
//      weights double-buffered via global_load_lds, 4 waves/SIMD ----
__global__ __launch_bounds__(512, 4) void ffn_kernel(
  const float* __restrict__ x, const char* __restrict__ wsw,
  const float* __restrict__ b1,
  const int* __restrict__ counts, const int* __restrict__ tok_ids,
  unsigned short* __restrict__ yslot)
{
  const int e    = blockIdx.x & 7;           // expert -> XCD pinning
  const int tile = blockIdx.x >> 3;
  const int cnt  = counts[e * 16];
  const int base = tile * MT;
  if (base >= cnt) return;

  __shared__ __align__(1024) unsigned short Ws[2][16384];  // 2 x 32KB
  __shared__ __align__(16)   float b1s[H_DIM];             // 4KB
  __shared__ int sTok[MT];

  const int tid = threadIdx.x, wave = tid >> 6, lane = tid & 63;
  const int mrow = lane & 15, qj = lane >> 4;
  const char* wexp = wsw + ((size_t)(e * NCHUNK) << 15);

  auto stage = [&](int c, int buf){
    const char* src = wexp + ((size_t)c << 15);
    char* dst = (char*)&Ws[buf][0];
#pragma unroll
    for (int i = 0; i < 4; ++i){
      int ub = i * 8192 + wave * 1024;       // wave-uniform LDS byte base
      __builtin_amdgcn_global_load_lds(
        (glb_u32*)(src + ub + lane * 16),
        (lds_u32*)(dst + ub), 16, 0, 0);
    }
  };

  if (tid < MT){
    int idx = base + tid;
    sTok[tid] = (idx < cnt) ? tok_ids[e*T_TOKENS + idx] : -1;
  }
  if (tid < 256) *(f32x4*)&b1s[tid * 4] = ((const f32x4*)(b1 + e*H_DIM))[tid];
  __syncthreads();

  stage(0, 0);

  // gather x B-fragments into registers (32 tokens/wave, full D)
  s16x8 afr[2][8];
#pragma unroll
  for (int ti = 0; ti < 2; ++ti){
    int ent = sTok[wave*32 + ti*16 + mrow];
    int tk = ent & 0xFFFF;
    const f32x4* src = (const f32x4*)(x + (size_t)(ent < 0 ? 0 : tk) * D_DIM);
#pragma unroll
    for (int k = 0; k < 8; ++k){
      f32x4 a = src[k*8 + qj*2];
      f32x4 b = src[k*8 + qj*2 + 1];
      s16x8 f;
      f[0]=(short)f2bf(a.x); f[1]=(short)f2bf(a.y); f[2]=(short)f2bf(a.z); f[3]=(short)f2bf(a.w);
      f[4]=(short)f2bf(b.x); f[5]=(short)f2bf(b.y); f[6]=(short)f2bf(b.z); f[7]=(short)f2bf(b.w);
      if (ent < 0) f = (s16x8)(short)0;
      afr[ti][k] = f;
    }
  }

  // per-lane LDS byte bases (swizzles are lane-constant)
  const int w1base = mrow*512 + ((qj*16) ^ ((mrow & 3) << 4)); // + mi*8192 + ((ks^sb)<<6)
  const int w1sb   = (mrow >> 2) & 1;
  const int w2base = 16384 + mrow*64 + ((qj*16) ^ (((mrow >> 1) & 3) << 4)); // + m*1024

  asm volatile("s_waitcnt vmcnt(0) lgkmcnt(0)" ::: "memory");
  __builtin_amdgcn_s_barrier();

  f32x4 yacc[16][2];
#pragma unroll
  for (int m = 0; m < 16; ++m){
    yacc[m][0] = (f32x4){0.f,0.f,0.f,0.f};
    yacc[m][1] = (f32x4){0.f,0.f,0.f,0.f};
  }

  int buf = 0;
#pragma unroll 1
  for (int c = 0; c < NCHUNK; ++c){
    if (c + 1 < NCHUNK) stage(c + 1, buf ^ 1);   // in flight across the chunk
    const char* Wb = (const char*)&Ws[buf][0];

    __builtin_amdgcn_s_setprio(1);

    // ---- layer 1 (swapped): hacc[mi][ti] = W1 x^T, D[h][token] ----
    f32x4 hacc[2][2];
    hacc[0][0] = (f32x4){0.f,0.f,0.f,0.f}; hacc[0][1] = (f32x4){0.f,0.f,0.f,0.f};
    hacc[1][0] = (f32x4){0.f,0.f,0.f,0.f}; hacc[1][1] = (f32x4){0.f,0.f,0.f,0.f};
#pragma unroll
    for (int ks = 0; ks < 8; ++ks){
      int ko = ((ks ^ w1sb) << 6);
      s16x8 w1a = *(const s16x8*)(Wb + w1base + ko);
      s16x8 w1b = *(const s16x8*)(Wb + 8192 + w1base + ko);
      hacc[0][0] = MFMA(w1a, afr[0][ks], hacc[0][0], 0, 0, 0);
      hacc[0][1] = MFMA(w1a, afr[1][ks], hacc[0][1], 0, 0, 0);
      hacc[1][0] = MFMA(w1b, afr[0][ks], hacc[1][0], 0, 0, 0);
      hacc[1][1] = MFMA(w1b, afr[1][ks], hacc[1][1], 0, 0, 0);
    }

    // ---- bias + relu + pack to bf16 B-fragments (in registers) ----
    f32x4 bv0 = *(const f32x4*)&b1s[c*32 + qj*4];
    f32x4 bv1 = *(const f32x4*)&b1s[c*32 + 16 + qj*4];
    s16x8 pb0, pb1;
    {
      f32x4 h0 = hacc[0][0], h1 = hacc[1][0];
      h0.x = fmaxf(h0.x + bv0.x, 0.f); h0.y = fmaxf(h0.y + bv0.y, 0.f);
      h0.z = fmaxf(h0.z + bv0.z, 0.f); h0.w = fmaxf(h0.w + bv0.w, 0.f);
      h1.x = fmaxf(h1.x + bv1.x, 0.f); h1.y = fmaxf(h1.y + bv1.y, 0.f);
      h1.z = fmaxf(h1.z + bv1.z, 0.f); h1.w = fmaxf(h1.w + bv1.w, 0.f);
      u32x4 pw;
      pw.x = cvtpk(h0.x, h0.y); pw.y = cvtpk(h0.z, h0.w);
      pw.z = cvtpk(h1.x, h1.y); pw.w = cvtpk(h1.z, h1.w);
      pb0 = __builtin_bit_cast(s16x8, pw);
    }
    {
      f32x4 h0 = hacc[0][1], h1 = hacc[1][1];
      h0.x = fmaxf(h0.x + bv0.x, 0.f); h0.y = fmaxf(h0.y + bv0.y, 0.f);
      h0.z = fmaxf(h0.z + bv0.z, 0.f); h0.w = fmaxf(h0.w + bv0.w, 0.f);
      h1.x = fmaxf(h1.x + bv1.x, 0.f); h1.y = fmaxf(h1.y + bv1.y, 0.f);
      h1.z = fmaxf(h1.z + bv1.z, 0.f); h1.w = fmaxf(h1.w + bv1.w, 0.f);
      u32x4 pw;
      pw.x = cvtpk(h0.x, h0.y); pw.y = cvtpk(h0.z, h0.w);
      pw.z = cvtpk(h1.x, h1.y); pw.w = cvtpk(h1.z, h1.w);
      pb1 = __builtin_bit_cast(s16x8, pw);
    }

    // ---- layer 2 (swapped, k-slot permuted W2): yacc[m][ti] D[d][token] ----
#pragma unroll
    for (int m = 0; m < 16; ++m){
      s16x8 w2f = *(const s16x8*)(Wb + w2base + m*1024);
      yacc[m][0] = MFMA(w2f, pb0, yacc[m][0], 0, 0, 0);
      yacc[m][1] = MFMA(w2f, pb1, yacc[m][1], 0, 0, 0);
    }

    __builtin_amdgcn_s_setprio(0);

    // one barrier per chunk: next chunk staged + this buffer free for reuse
    asm volatile("s_waitcnt vmcnt(0)" ::: "memory");
    __builtin_amdgcn_s_barrier();
    buf ^= 1;
  }

  // ---- store: yslot[2*tok+which][d] = bf16(y), packed b32, no atomics ----
#pragma unroll
  for (int ti = 0; ti < 2; ++ti){
    int ent = sTok[wave*32 + ti*16 + mrow];
    if (ent < 0) continue;
    int slot = ((ent & 0xFFFF) << 1) | ((ent >> 16) & 1);
    unsigned short* dst = yslot + (size_t)slot * 256;
#pragma unroll
    for (int m = 0; m < 16; ++m){
      unsigned lo = cvtpk(yacc[m][ti][0], yacc[m][ti][1]);
      unsigned hi = cvtpk(yacc[m][ti][2], yacc[m][ti][3]);
      *(unsigned*)(dst + m*16 + qj*4)     = lo;   // d = m*16 + qj*4 + {0,1}
      *(unsigned*)(dst + m*16 + qj*4 + 2) = hi;   // d = ... + {2,3}
    }
  }
}

// ---- combine: out[t] = p0*(y0+b2[e0]) + p1*(y1+b2[e1]); in-place over slots ----
__global__ __launch_bounds__(256) void combine_kernel(
    const float* __restrict__ rrec, const float* __restrict__ b2,
    float* __restrict__ out)
{
  int t = blockIdx.x * 4 + (threadIdx.x >> 6);
  int lane = threadIdx.x & 63;
  f32x4 rr = *(const f32x4*)(rrec + (size_t)t * 4);
  float p0 = rr.x, p1 = rr.y;
  int e0 = (int)rr.z, e1 = (int)rr.w;
  const u16x4* s0 = (const u16x4*)((const unsigned short*)out + (size_t)t * 512);
  u16x4 a = s0[lane];        // slot 2t   : cols lane*4..+3
  u16x4 b = s0[64 + lane];   // slot 2t+1
  f32x4 z0 = *(const f32x4*)(b2 + e0*D_DIM + 4*lane);
  f32x4 z1 = *(const f32x4*)(b2 + e1*D_DIM + 4*lane);
  f32x4 o;
  o.x = p0*(bf2f(a.x) + z0.x) + p1*(bf2f(b.x) + z1.x);
  o.y = p0*(bf2f(a.y) + z0.y) + p1*(bf2f(b.y) + z1.y);
  o.z = p0*(bf2f(a.z) + z0.z) + p1*(bf2f(b.z) + z1.z);
  o.w = p0*(bf2f(a.w) + z0.w) + p1*(bf2f(b.w) + z1.w);
  *(f32x4*)(out + (size_t)t * D_DIM + 4*lane) = o;
}

extern "C" void kernel_launch(void* const* d_in, const int* in_sizes, int n_in,
                              void* d_out, int out_size, void* d_ws, size_t ws_size,
                              hipStream_t stream) {
  const float* x  = (const float*)d_in[0];
  const float* Wg = (const float*)d_in[1];
  const float* bg = (const float*)d_in[2];
  const float* W1 = (const float*)d_in[3];
  const float* b1 = (const float*)d_in[4];
  const float* W2 = (const float*)d_in[5];
  const float* b2 = (const float*)d_in[6];
  float* out = (float*)d_out;
  char* ws = (char*)d_ws;

  char*  wsw     = ws;                        // 8,388,608 B swizzled weights
  int*   counts  = (int*)  (ws + 8388608);    // 512 B (8 x 64B lines)
  int*   tok_ids = (int*)  (ws + 8389632);    // 2,097,152 B
  float* rrec    = (float*)(ws + 10486784);   // 1,048,576 B (f32x4 per token)

  hipMemsetAsync(counts, 0, 512, stream);
  gate_kernel<<<T_TOKENS/GTB, 256, 0, stream>>>(x, Wg, bg, W1, W2, wsw,
                                                counts, tok_ids, rrec);
  ffn_kernel<<<E_NUM * (T_TOKENS/MT), 512, 0, stream>>>(x, wsw, b1, counts, tok_ids,
                                                        (unsigned short*)d_out);
  combine_kernel<<<T_TOKENS/4, 256, 0, stream>>>(rrec, b2, out);
}

// Round 7
// 549.972 us; speedup vs baseline: 1.9232x; 1.9232x over previous
//
#include <hip/hip_runtime.h>
#include <hip/hip_bf16.h>

#define T_TOKENS 65536
#define D_DIM 256
#define H_DIM 1024
#define E_NUM 8
#define MT 128
#define HC 32
#define NCHUNK 32              // H_DIM / HC
#define GTB 64                 // gate tokens per block

typedef __attribute__((ext_vector_type(4))) float f32x4;
typedef __attribute__((ext_vector_type(8))) short s16x8;
typedef __attribute__((ext_vector_type(4))) unsigned int u32x4;
typedef __attribute__((ext_vector_type(4))) unsigned short u16x4;
typedef __attribute__((address_space(3))) unsigned int lds_u32;
typedef const __attribute__((address_space(1))) unsigned int glb_u32;

#define MFMA __builtin_amdgcn_mfma_f32_16x16x32_bf16

__device__ __forceinline__ unsigned short f2bf(float f){
  union { float f; unsigned u; } v; v.f = f;
  unsigned r = v.u + 0x7FFFu + ((v.u >> 16) & 1u);
  return (unsigned short)(r >> 16);
}
__device__ __forceinline__ float bf2f(unsigned short h){
  return __uint_as_float((unsigned)h << 16);
}
__device__ __forceinline__ unsigned cvtpk(float lo, float hi){
  unsigned r;
  asm("v_cvt_pk_bf16_f32 %0, %1, %2" : "=v"(r) : "v"(lo), "v"(hi));
  return r;
}
__device__ __forceinline__ unsigned long long pack4(f32x4 v){
  return (unsigned long long)f2bf(v.x)
       | ((unsigned long long)f2bf(v.y) << 16)
       | ((unsigned long long)f2bf(v.z) << 32)
       | ((unsigned long long)f2bf(v.w) << 48);
}

// one 4-float unit of weight conversion into the swizzled chunk image.
// chunk(e,c) = 32KB: [W1c: 32 h-rows x 256 d, row 512B, swz (h&7)<<4]
//  + [W2p at +16384: 256 d-rows x 32 h-slots, row 64B, slot s=qj*8+mi*4+j
//     holding W2[d][mi*16+qj*4+j], swz ((d>>1)&3)<<4]
__device__ __forceinline__ void cvt_unit(int i, const float* __restrict__ W1,
                                         const float* __restrict__ W2,
                                         char* __restrict__ wsw){
  const int N1 = (E_NUM * H_DIM * D_DIM) / 4;      // 524288
  unsigned long long pk;
  size_t off;
  if (i < N1){
    pk = pack4(((const f32x4*)W1)[i]);
    int idx = i << 2;
    int e  = idx >> 18;
    int h  = (idx >> 8) & (H_DIM - 1);
    int d0 = idx & (D_DIM - 1);
    int c = h >> 5, r = h & 31;
    off = ((size_t)(e * NCHUNK + c) << 15)
        + (size_t)(((r << 9) + (d0 << 1)) ^ ((r & 7) << 4));
  } else {
    pk = pack4(((const f32x4*)W2)[i - N1]);
    int idx = (i - N1) << 2;
    int e  = idx >> 18;
    int d  = (idx >> 10) & (D_DIM - 1);
    int h0 = idx & (H_DIM - 1);
    int c  = h0 >> 5;
    int mi = (h0 >> 4) & 1, qjs = (h0 >> 2) & 3;
    int s2 = qjs * 16 + mi * 8;                    // byte offset of the 8B slot group
    off = ((size_t)(e * NCHUNK + c) << 15) + 16384
        + (size_t)((d << 6) + (s2 ^ (((d >> 1) & 3) << 4)));
  }
  *(unsigned long long*)(wsw + off) = pk;
}

// ---- gate (+fused weight conversion): scores, top-2, softmax, routing ----
__global__ __launch_bounds__(256) void gate_kernel(
    const float* __restrict__ x, const float* __restrict__ Wg,
    const float* __restrict__ bg,
    const float* __restrict__ W1, const float* __restrict__ W2,
    char* __restrict__ wsw,
    int* __restrict__ counts, int* __restrict__ tok_ids, float* __restrict__ rrec)
{
  __shared__ int lcnt[E_NUM];
  __shared__ int lbase[E_NUM];
  __shared__ unsigned char aexp[GTB * 2];
  __shared__ short         apos[GTB * 2];

  int tid = threadIdx.x, wave = tid >> 6, lane = tid & 63;

  // fused weight conversion: 4 units per thread
  int gthr = blockIdx.x * 256 + tid;
#pragma unroll
  for (int j = 0; j < 4; ++j)
    cvt_unit(gthr + j * ((T_TOKENS / GTB) * 256), W1, W2, wsw);

  if (tid < E_NUM) lcnt[tid] = 0;
  __syncthreads();

  int t0 = blockIdx.x * GTB;
#pragma unroll 1
  for (int i = 0; i < GTB / 4; ++i){
    int tl = wave * (GTB / 4) + i;
    int t = t0 + tl;
    f32x4 xv = *(const f32x4*)(x + (size_t)t * D_DIM + 4*lane);
    float s[E_NUM];
#pragma unroll
    for (int e = 0; e < E_NUM; ++e){
      f32x4 w = *(const f32x4*)(Wg + e*D_DIM + 4*lane);
      s[e] = xv.x*w.x + xv.y*w.y + xv.z*w.z + xv.w*w.w;
    }
#pragma unroll
    for (int off = 32; off; off >>= 1){
#pragma unroll
      for (int e = 0; e < E_NUM; ++e) s[e] += __shfl_xor(s[e], off);
    }
#pragma unroll
    for (int e = 0; e < E_NUM; ++e) s[e] += bg[e];
    int e0 = 0; float v0 = s[0];
#pragma unroll
    for (int e = 1; e < E_NUM; ++e) if (s[e] > v0){ v0 = s[e]; e0 = e; }
    int e1 = -1; float v1 = -3.4e38f;
#pragma unroll
    for (int e = 0; e < E_NUM; ++e){
      if (e == e0) continue;
      if (s[e] > v1){ v1 = s[e]; e1 = e; }
    }
    float ex = __expf(v1 - v0);
    float inv = 1.f / (1.f + ex);
    float p0 = inv, p1 = ex * inv;
    if (lane == 0){
      int li = tl * 2;
      int pos0 = atomicAdd(&lcnt[e0], 1);
      int pos1 = atomicAdd(&lcnt[e1], 1);
      aexp[li]   = (unsigned char)e0; apos[li]   = (short)pos0;
      aexp[li+1] = (unsigned char)e1; apos[li+1] = (short)pos1;
      f32x4 rr; rr.x = p0; rr.y = p1; rr.z = (float)e0; rr.w = (float)e1;
      *(f32x4*)(rrec + (size_t)t * 4) = rr;
    }
  }
  __syncthreads();
  if (tid < E_NUM) lbase[tid] = atomicAdd(counts + tid*16, lcnt[tid]);
  __syncthreads();
  if (tid < GTB * 2){
    int t = t0 + (tid >> 1);
    int e = aexp[tid];
    int idx = lbase[e] + apos[tid];
    tok_ids[e*T_TOKENS + idx] = t | ((tid & 1) << 16);   // token | which-bit
  }
}

// ---- grouped FFN: 128 tokens/block, 4 waves x 32 tokens, h in registers.
//      W1 single-buffered (restaged per chunk after phase barrier),
//      W2 double-buffered; counted vmcnt; 3 blocks/CU. ----
__global__ __launch_bounds__(256, 3) void ffn_kernel(
  const float* __restrict__ x, const char* __restrict__ wsw,
  const float* __restrict__ b1,
  const int* __restrict__ counts, const int* __restrict__ tok_ids,
  unsigned short* __restrict__ yslot)
{
  const int e    = blockIdx.x & 7;           // expert -> XCD pinning
  const int tile = blockIdx.x >> 3;
  const int cnt  = counts[e * 16];
  const int base = tile * MT;
  if (base >= cnt) return;

  __shared__ __align__(1024) unsigned short W1s[8192];      // 16KB single
  __shared__ __align__(1024) unsigned short W2s[2][8192];   // 2 x 16KB
  __shared__ __align__(16)   float b1s[H_DIM];              // 4KB
  __shared__ int sTok[MT];                                  // 512B

  const int tid = threadIdx.x, wave = tid >> 6, lane = tid & 63;
  const int mrow = lane & 15, qj = lane >> 4;
  const char* wexp = wsw + ((size_t)(e * NCHUNK) << 15);

  auto stage_w1 = [&](int c){
    const char* src = wexp + ((size_t)c << 15);
#pragma unroll
    for (int i = 0; i < 4; ++i){
      int ub = i * 4096 + wave * 1024;
      __builtin_amdgcn_global_load_lds(
        (glb_u32*)(src + ub + lane * 16),
        (lds_u32*)((char*)W1s + ub), 16, 0, 0);
    }
  };
  auto stage_w2 = [&](int c, int buf){
    const char* src = wexp + ((size_t)c << 15) + 16384;
    char* dst = (char*)&W2s[buf][0];
#pragma unroll
    for (int i = 0; i < 4; ++i){
      int ub = i * 4096 + wave * 1024;
      __builtin_amdgcn_global_load_lds(
        (glb_u32*)(src + ub + lane * 16),
        (lds_u32*)(dst + ub), 16, 0, 0);
    }
  };

  if (tid < MT){
    int idx = base + tid;
    sTok[tid] = (idx < cnt) ? tok_ids[e*T_TOKENS + idx] : -1;
  }
  *(f32x4*)&b1s[tid * 4] = ((const f32x4*)(b1 + e*H_DIM))[tid];
  __syncthreads();

  // prologue: stage chunk 0 (W1 first, then W2 -> vmcnt order)
  stage_w1(0);
  stage_w2(0, 0);

  // gather x B-fragments into registers (32 tokens/wave, full D)
  s16x8 afr[2][8];
#pragma unroll
  for (int ti = 0; ti < 2; ++ti){
    int ent = sTok[wave*32 + ti*16 + mrow];
    int tk = ent & 0xFFFF;
    const f32x4* src = (const f32x4*)(x + (size_t)(ent < 0 ? 0 : tk) * D_DIM);
#pragma unroll
    for (int k = 0; k < 8; ++k){
      f32x4 a = src[k*8 + qj*2];
      f32x4 b = src[k*8 + qj*2 + 1];
      s16x8 f;
      f[0]=(short)f2bf(a.x); f[1]=(short)f2bf(a.y); f[2]=(short)f2bf(a.z); f[3]=(short)f2bf(a.w);
      f[4]=(short)f2bf(b.x); f[5]=(short)f2bf(b.y); f[6]=(short)f2bf(b.z); f[7]=(short)f2bf(b.w);
      if (ent < 0) f = (s16x8)(short)0;
      afr[ti][k] = f;
    }
  }

  // per-lane LDS byte bases (swizzles are lane-constant)
  const int w1base = mrow*512 + ((qj*16) ^ ((mrow & 3) << 4)); // + mi*8192 + ((ks^sb)<<6)
  const int w1sb   = (mrow >> 2) & 1;
  const int w2base = mrow*64 + ((qj*16) ^ (((mrow >> 1) & 3) << 4)); // + m*1024

  // wait: W1(0) landed (own 4 oldest loads); gather loads auto-waited by compiler;
  // W2(0)'s 4 may still fly -> caught by vmcnt(0) inside chunk 0
  asm volatile("s_waitcnt vmcnt(4)" ::: "memory");
  __builtin_amdgcn_s_barrier();

  f32x4 yacc[16][2];
#pragma unroll
  for (int m = 0; m < 16; ++m){
    yacc[m][0] = (f32x4){0.f,0.f,0.f,0.f};
    yacc[m][1] = (f32x4){0.f,0.f,0.f,0.f};
  }

  int cur = 0;
#pragma unroll 1
  for (int c = 0; c < NCHUNK; ++c){
    const char* Wb = (const char*)W1s;

    // ---- phase 1: h = W1(c) x^T  (reads W1s only) ----
    __builtin_amdgcn_s_setprio(1);
    f32x4 hacc[2][2];
    hacc[0][0] = (f32x4){0.f,0.f,0.f,0.f}; hacc[0][1] = (f32x4){0.f,0.f,0.f,0.f};
    hacc[1][0] = (f32x4){0.f,0.f,0.f,0.f}; hacc[1][1] = (f32x4){0.f,0.f,0.f,0.f};
#pragma unroll
    for (int ks = 0; ks < 8; ++ks){
      int ko = ((ks ^ w1sb) << 6);
      s16x8 w1a = *(const s16x8*)(Wb + w1base + ko);
      s16x8 w1b = *(const s16x8*)(Wb + 8192 + w1base + ko);
      hacc[0][0] = MFMA(w1a, afr[0][ks], hacc[0][0], 0, 0, 0);
      hacc[0][1] = MFMA(w1a, afr[1][ks], hacc[0][1], 0, 0, 0);
      hacc[1][0] = MFMA(w1b, afr[0][ks], hacc[1][0], 0, 0, 0);
      hacc[1][1] = MFMA(w1b, afr[1][ks], hacc[1][1], 0, 0, 0);
    }

    // ---- bias + relu + pack to bf16 B-fragments (in registers) ----
    f32x4 bv0 = *(const f32x4*)&b1s[c*32 + qj*4];
    f32x4 bv1 = *(const f32x4*)&b1s[c*32 + 16 + qj*4];
    s16x8 pb0, pb1;
    {
      f32x4 h0 = hacc[0][0], h1 = hacc[1][0];
      h0.x = fmaxf(h0.x + bv0.x, 0.f); h0.y = fmaxf(h0.y + bv0.y, 0.f);
      h0.z = fmaxf(h0.z + bv0.z, 0.f); h0.w = fmaxf(h0.w + bv0.w, 0.f);
      h1.x = fmaxf(h1.x + bv1.x, 0.f); h1.y = fmaxf(h1.y + bv1.y, 0.f);
      h1.z = fmaxf(h1.z + bv1.z, 0.f); h1.w = fmaxf(h1.w + bv1.w, 0.f);
      u32x4 pw;
      pw.x = cvtpk(h0.x, h0.y); pw.y = cvtpk(h0.z, h0.w);
      pw.z = cvtpk(h1.x, h1.y); pw.w = cvtpk(h1.z, h1.w);
      pb0 = __builtin_bit_cast(s16x8, pw);
    }
    {
      f32x4 h0 = hacc[0][1], h1 = hacc[1][1];
      h0.x = fmaxf(h0.x + bv0.x, 0.f); h0.y = fmaxf(h0.y + bv0.y, 0.f);
      h0.z = fmaxf(h0.z + bv0.z, 0.f); h0.w = fmaxf(h0.w + bv0.w, 0.f);
      h1.x = fmaxf(h1.x + bv1.x, 0.f); h1.y = fmaxf(h1.y + bv1.y, 0.f);
      h1.z = fmaxf(h1.z + bv1.z, 0.f); h1.w = fmaxf(h1.w + bv1.w, 0.f);
      u32x4 pw;
      pw.x = cvtpk(h0.x, h0.y); pw.y = cvtpk(h0.z, h0.w);
      pw.z = cvtpk(h1.x, h1.y); pw.w = cvtpk(h1.z, h1.w);
      pb1 = __builtin_bit_cast(s16x8, pw);
    }
    __builtin_amdgcn_s_setprio(0);

    // own W2(c) stage (issued last chunk) complete; + all waves done reading W1s
    asm volatile("s_waitcnt vmcnt(0)" ::: "memory");
    __builtin_amdgcn_s_barrier();          // barrier #1

    // issue next chunk's staging: W1 first (into W1s), then W2 (into cur^1)
    if (c + 1 < NCHUNK){
      stage_w1(c + 1);
      stage_w2(c + 1, cur ^ 1);
    }

    // ---- phase 2: y += W2p(c) h  (reads W2s[cur] only) ----
    __builtin_amdgcn_s_setprio(1);
    const char* W2c = (const char*)&W2s[cur][0];
#pragma unroll
    for (int m = 0; m < 16; ++m){
      s16x8 w2f = *(const s16x8*)(W2c + w2base + m*1024);
      yacc[m][0] = MFMA(w2f, pb0, yacc[m][0], 0, 0, 0);
      yacc[m][1] = MFMA(w2f, pb1, yacc[m][1], 0, 0, 0);
    }
    __builtin_amdgcn_s_setprio(0);

    // own W1(c+1) landed (4 oldest); W2(c+1)'s 4 still in flight
    asm volatile("s_waitcnt vmcnt(4)" ::: "memory");
    __builtin_amdgcn_s_barrier();          // barrier #2: next L1 safe
    cur ^= 1;
  }

  // ---- store: yslot[2*tok+which][d] = bf16(y), packed b32, no atomics ----
#pragma unroll
  for (int ti = 0; ti < 2; ++ti){
    int ent = sTok[wave*32 + ti*16 + mrow];
    if (ent < 0) continue;
    int slot = ((ent & 0xFFFF) << 1) | ((ent >> 16) & 1);
    unsigned short* dst = yslot + (size_t)slot * 256;
#pragma unroll
    for (int m = 0; m < 16; ++m){
      unsigned lo = cvtpk(yacc[m][ti][0], yacc[m][ti][1]);
      unsigned hi = cvtpk(yacc[m][ti][2], yacc[m][ti][3]);
      *(unsigned*)(dst + m*16 + qj*4)     = lo;   // d = m*16 + qj*4 + {0,1}
      *(unsigned*)(dst + m*16 + qj*4 + 2) = hi;   // d = ... + {2,3}
    }
  }
}

// ---- combine: out[t] = p0*(y0+b2[e0]) + p1*(y1+b2[e1]); in-place over slots ----
__global__ __launch_bounds__(256) void combine_kernel(
    const float* __restrict__ rrec, const float* __restrict__ b2,
    float* __restrict__ out)
{
  int t = blockIdx.x * 4 + (threadIdx.x >> 6);
  int lane = threadIdx.x & 63;
  f32x4 rr = *(const f32x4*)(rrec + (size_t)t * 4);
  float p0 = rr.x, p1 = rr.y;
  int e0 = (int)rr.z, e1 = (int)rr.w;
  const u16x4* s0 = (const u16x4*)((const unsigned short*)out + (size_t)t * 512);
  u16x4 a = s0[lane];        // slot 2t   : cols lane*4..+3
  u16x4 b = s0[64 + lane];   // slot 2t+1
  f32x4 z0 = *(const f32x4*)(b2 + e0*D_DIM + 4*lane);
  f32x4 z1 = *(const f32x4*)(b2 + e1*D_DIM + 4*lane);
  f32x4 o;
  o.x = p0*(bf2f(a.x) + z0.x) + p1*(bf2f(b.x) + z1.x);
  o.y = p0*(bf2f(a.y) + z0.y) + p1*(bf2f(b.y) + z1.y);
  o.z = p0*(bf2f(a.z) + z0.z) + p1*(bf2f(b.z) + z1.z);
  o.w = p0*(bf2f(a.w) + z0.w) + p1*(bf2f(b.w) + z1.w);
  *(f32x4*)(out + (size_t)t * D_DIM + 4*lane) = o;
}

extern "C" void kernel_launch(void* const* d_in, const int* in_sizes, int n_in,
                              void* d_out, int out_size, void* d_ws, size_t ws_size,
                              hipStream_t stream) {
  const float* x  = (const float*)d_in[0];
  const float* Wg = (const float*)d_in[1];
  const float* bg = (const float*)d_in[2];
  const float* W1 = (const float*)d_in[3];
  const float* b1 = (const float*)d_in[4];
  const float* W2 = (const float*)d_in[5];
  const float* b2 = (const float*)d_in[6];
  float* out = (float*)d_out;
  char* ws = (char*)d_ws;

  char*  wsw     = ws;                        // 8,388,608 B swizzled weights
  int*   counts  = (int*)  (ws + 8388608);    // 512 B (8 x 64B lines)
  int*   tok_ids = (int*)  (ws + 8389632);    // 2,097,152 B
  float* rrec    = (float*)(ws + 10486784);   // 1,048,576 B (f32x4 per token)

  hipMemsetAsync(counts, 0, 512, stream);
  gate_kernel<<<T_TOKENS/GTB, 256, 0, stream>>>(x, Wg, bg, W1, W2, wsw,
                                                counts, tok_ids, rrec);
  ffn_kernel<<<E_NUM * (T_TOKENS/MT), 256, 0, stream>>>(x, wsw, b1, counts, tok_ids,
                                                        (unsigned short*)d_out);
  combine_kernel<<<T_TOKENS/4, 256, 0, stream>>>(rrec, b2, out);
}

// Round 8
// 408.687 us; speedup vs baseline: 2.5881x; 1.3457x over previous
//
#include <hip/hip_runtime.h>
#include <hip/hip_bf16.h>

#define T_TOKENS 65536
#define D_DIM 256
#define H_DIM 1024
#define E_NUM 8
#define MT 128
#define HC 32
#define NCHUNK 32              // H_DIM / HC
#define GTB 64                 // gate tokens per block

typedef __attribute__((ext_vector_type(4))) float f32x4;
typedef __attribute__((ext_vector_type(8))) short s16x8;
typedef __attribute__((ext_vector_type(4))) unsigned int u32x4;
typedef __attribute__((ext_vector_type(4))) unsigned short u16x4;
typedef __attribute__((address_space(3))) unsigned int lds_u32;
typedef const __attribute__((address_space(1))) unsigned int glb_u32;

#define MFMA __builtin_amdgcn_mfma_f32_16x16x32_bf16

__device__ __forceinline__ unsigned short f2bf(float f){
  union { float f; unsigned u; } v; v.f = f;
  unsigned r = v.u + 0x7FFFu + ((v.u >> 16) & 1u);
  return (unsigned short)(r >> 16);
}
__device__ __forceinline__ float bf2f(unsigned short h){
  return __uint_as_float((unsigned)h << 16);
}
__device__ __forceinline__ unsigned cvtpk(float lo, float hi){
  unsigned r;
  asm("v_cvt_pk_bf16_f32 %0, %1, %2" : "=v"(r) : "v"(lo), "v"(hi));
  return r;
}
__device__ __forceinline__ unsigned long long pack4(f32x4 v){
  return (unsigned long long)f2bf(v.x)
       | ((unsigned long long)f2bf(v.y) << 16)
       | ((unsigned long long)f2bf(v.z) << 32)
       | ((unsigned long long)f2bf(v.w) << 48);
}

// one 4-float unit of weight conversion into the chunked image.
// chunk(e,c) = 32KB:
//  [W1c: 32 h-rows x 256 d, row 512B, composed swizzle ^((r&7)<<4)]  (LDS-staged)
//  [W2p at +16384: 16 m-tiles x 1KB, lane-major: byte = m*1024 + lane*16 + j'*2,
//   lane = qj*16 + (d&15), j' = mi*4 + j, holding W2[d = m*16+(d&15)][mi*16+qj*4+j]]
//   (read directly global->VGPR, perfectly coalesced per wave)
__device__ __forceinline__ void cvt_unit(int i, const float* __restrict__ W1,
                                         const float* __restrict__ W2,
                                         char* __restrict__ wsw){
  const int N1 = (E_NUM * H_DIM * D_DIM) / 4;      // 524288
  unsigned long long pk;
  size_t off;
  if (i < N1){
    pk = pack4(((const f32x4*)W1)[i]);
    int idx = i << 2;
    int e  = idx >> 18;
    int h  = (idx >> 8) & (H_DIM - 1);
    int d0 = idx & (D_DIM - 1);
    int c = h >> 5, r = h & 31;
    off = ((size_t)(e * NCHUNK + c) << 15)
        + (size_t)(((r << 9) + (d0 << 1)) ^ ((r & 7) << 4));
  } else {
    pk = pack4(((const f32x4*)W2)[i - N1]);
    int idx = (i - N1) << 2;
    int e   = idx >> 18;
    int d   = (idx >> 10) & (D_DIM - 1);
    int h0  = idx & (H_DIM - 1);
    int c   = h0 >> 5;
    int h32 = h0 & 31;
    int mi = (h32 >> 4) & 1, qj = (h32 >> 2) & 3;
    off = ((size_t)(e * NCHUNK + c) << 15) + 16384
        + (size_t)(((d >> 4) << 10) + ((qj * 16 + (d & 15)) << 4) + (mi << 3));
  }
  *(unsigned long long*)(wsw + off) = pk;
}

// ---- gate (+fused weight conversion): scores, top-2, softmax, routing ----
__global__ __launch_bounds__(256) void gate_kernel(
    const float* __restrict__ x, const float* __restrict__ Wg,
    const float* __restrict__ bg,
    const float* __restrict__ W1, const float* __restrict__ W2,
    char* __restrict__ wsw,
    int* __restrict__ counts, int* __restrict__ tok_ids, float* __restrict__ rrec)
{
  __shared__ int lcnt[E_NUM];
  __shared__ int lbase[E_NUM];
  __shared__ unsigned char aexp[GTB * 2];
  __shared__ short         apos[GTB * 2];

  int tid = threadIdx.x, wave = tid >> 6, lane = tid & 63;

  // fused weight conversion: 4 units per thread
  int gthr = blockIdx.x * 256 + tid;
#pragma unroll
  for (int j = 0; j < 4; ++j)
    cvt_unit(gthr + j * ((T_TOKENS / GTB) * 256), W1, W2, wsw);

  if (tid < E_NUM) lcnt[tid] = 0;
  __syncthreads();

  int t0 = blockIdx.x * GTB;
#pragma unroll 1
  for (int i = 0; i < GTB / 4; ++i){
    int tl = wave * (GTB / 4) + i;
    int t = t0 + tl;
    f32x4 xv = *(const f32x4*)(x + (size_t)t * D_DIM + 4*lane);
    float s[E_NUM];
#pragma unroll
    for (int e = 0; e < E_NUM; ++e){
      f32x4 w = *(const f32x4*)(Wg + e*D_DIM + 4*lane);
      s[e] = xv.x*w.x + xv.y*w.y + xv.z*w.z + xv.w*w.w;
    }
#pragma unroll
    for (int off = 32; off; off >>= 1){
#pragma unroll
      for (int e = 0; e < E_NUM; ++e) s[e] += __shfl_xor(s[e], off);
    }
#pragma unroll
    for (int e = 0; e < E_NUM; ++e) s[e] += bg[e];
    int e0 = 0; float v0 = s[0];
#pragma unroll
    for (int e = 1; e < E_NUM; ++e) if (s[e] > v0){ v0 = s[e]; e0 = e; }
    int e1 = -1; float v1 = -3.4e38f;
#pragma unroll
    for (int e = 0; e < E_NUM; ++e){
      if (e == e0) continue;
      if (s[e] > v1){ v1 = s[e]; e1 = e; }
    }
    float ex = __expf(v1 - v0);
    float inv = 1.f / (1.f + ex);
    float p0 = inv, p1 = ex * inv;
    if (lane == 0){
      int li = tl * 2;
      int pos0 = atomicAdd(&lcnt[e0], 1);
      int pos1 = atomicAdd(&lcnt[e1], 1);
      aexp[li]   = (unsigned char)e0; apos[li]   = (short)pos0;
      aexp[li+1] = (unsigned char)e1; apos[li+1] = (short)pos1;
      f32x4 rr; rr.x = p0; rr.y = p1; rr.z = (float)e0; rr.w = (float)e1;
      *(f32x4*)(rrec + (size_t)t * 4) = rr;
    }
  }
  __syncthreads();
  if (tid < E_NUM) lbase[tid] = atomicAdd(counts + tid*16, lcnt[tid]);
  __syncthreads();
  if (tid < GTB * 2){
    int t = t0 + (tid >> 1);
    int e = aexp[tid];
    int idx = lbase[e] + apos[tid];
    tok_ids[e*T_TOKENS + idx] = t | ((tid & 1) << 16);   // token | which-bit
  }
}

// ---- grouped FFN: 128 tokens/block, 4 waves x 32 tokens, h in registers.
//      W1 double-buffered in LDS (2x16KB); W2 streamed L2/L1 -> VGPR
//      (separate pipe from LDS); one barrier per chunk; 2 waves/SIMD. ----
__global__ __launch_bounds__(256, 2) void ffn_kernel(
  const float* __restrict__ x, const char* __restrict__ wsw,
  const float* __restrict__ b1,
  const int* __restrict__ counts, const int* __restrict__ tok_ids,
  unsigned short* __restrict__ yslot)
{
  const int e    = blockIdx.x & 7;           // expert -> XCD pinning
  const int tile = blockIdx.x >> 3;
  const int cnt  = counts[e * 16];
  const int base = tile * MT;
  if (base >= cnt) return;

  __shared__ __align__(1024) unsigned short W1s[2][8192];   // 2 x 16KB
  __shared__ __align__(16)   float b1s[H_DIM];              // 4KB
  __shared__ int sTok[MT];                                  // 512B

  const int tid = threadIdx.x, wave = tid >> 6, lane = tid & 63;
  const int mrow = lane & 15, qj = lane >> 4;
  const char* wexp = wsw + ((size_t)(e * NCHUNK) << 15);

  auto stage_w1 = [&](int c, int buf){
    const char* src = wexp + ((size_t)c << 15);
    char* dst = (char*)&W1s[buf][0];
#pragma unroll
    for (int i = 0; i < 4; ++i){
      int ub = i * 4096 + wave * 1024;
      __builtin_amdgcn_global_load_lds(
        (glb_u32*)(src + ub + lane * 16),
        (lds_u32*)(dst + ub), 16, 0, 0);
    }
  };

  if (tid < MT){
    int idx = base + tid;
    sTok[tid] = (idx < cnt) ? tok_ids[e*T_TOKENS + idx] : -1;
  }
  *(f32x4*)&b1s[tid * 4] = ((const f32x4*)(b1 + e*H_DIM))[tid];
  __syncthreads();

  // prologue: stage W1 chunk 0
  stage_w1(0, 0);

  // gather x B-fragments into registers (32 tokens/wave, full D)
  s16x8 afr[2][8];
#pragma unroll
  for (int ti = 0; ti < 2; ++ti){
    int ent = sTok[wave*32 + ti*16 + mrow];
    int tk = ent & 0xFFFF;
    const f32x4* src = (const f32x4*)(x + (size_t)(ent < 0 ? 0 : tk) * D_DIM);
#pragma unroll
    for (int k = 0; k < 8; ++k){
      f32x4 a = src[k*8 + qj*2];
      f32x4 b = src[k*8 + qj*2 + 1];
      s16x8 f;
      f[0]=(short)f2bf(a.x); f[1]=(short)f2bf(a.y); f[2]=(short)f2bf(a.z); f[3]=(short)f2bf(a.w);
      f[4]=(short)f2bf(b.x); f[5]=(short)f2bf(b.y); f[6]=(short)f2bf(b.z); f[7]=(short)f2bf(b.w);
      if (ent < 0) f = (s16x8)(short)0;
      afr[ti][k] = f;
    }
  }

  // per-lane LDS byte base for W1 (composed swizzle, lane-constant)
  const int w1base = mrow*512 + ((qj*16) ^ ((mrow & 3) << 4)); // + mi*8192 + ((ks^sb)<<6)
  const int w1sb   = (mrow >> 2) & 1;

  asm volatile("s_waitcnt vmcnt(0) lgkmcnt(0)" ::: "memory");
  __builtin_amdgcn_s_barrier();

  f32x4 yacc[16][2];
#pragma unroll
  for (int m = 0; m < 16; ++m){
    yacc[m][0] = (f32x4){0.f,0.f,0.f,0.f};
    yacc[m][1] = (f32x4){0.f,0.f,0.f,0.f};
  }

  int buf = 0;
#pragma unroll 1
  for (int c = 0; c < NCHUNK; ++c){
    // issue next W1 stage first (stays oldest in vmcnt queue)
    if (c + 1 < NCHUNK) stage_w1(c + 1, buf ^ 1);

    // W2 fragments for this chunk: direct global->VGPR, coalesced 16B/lane.
    // Pre-issue the first 4 m-tiles; their latency hides under phase 1.
    const s16x8* w2c = (const s16x8*)(wexp + (((size_t)c) << 15) + 16384) + lane;
    s16x8 wfa = w2c[0], wfb = w2c[64], wfc = w2c[128], wfd = w2c[192];

    const char* Wb = (const char*)&W1s[buf][0];

    // ---- phase 1: h = W1(c) x^T  (LDS reads only) ----
    __builtin_amdgcn_s_setprio(1);
    f32x4 hacc[2][2];
    hacc[0][0] = (f32x4){0.f,0.f,0.f,0.f}; hacc[0][1] = (f32x4){0.f,0.f,0.f,0.f};
    hacc[1][0] = (f32x4){0.f,0.f,0.f,0.f}; hacc[1][1] = (f32x4){0.f,0.f,0.f,0.f};
#pragma unroll
    for (int ks = 0; ks < 8; ++ks){
      int ko = ((ks ^ w1sb) << 6);
      s16x8 w1a = *(const s16x8*)(Wb + w1base + ko);
      s16x8 w1b = *(const s16x8*)(Wb + 8192 + w1base + ko);
      hacc[0][0] = MFMA(w1a, afr[0][ks], hacc[0][0], 0, 0, 0);
      hacc[0][1] = MFMA(w1a, afr[1][ks], hacc[0][1], 0, 0, 0);
      hacc[1][0] = MFMA(w1b, afr[0][ks], hacc[1][0], 0, 0, 0);
      hacc[1][1] = MFMA(w1b, afr[1][ks], hacc[1][1], 0, 0, 0);
    }
    __builtin_amdgcn_s_setprio(0);

    // ---- bias + relu + pack to bf16 B-fragments (in registers) ----
    f32x4 bv0 = *(const f32x4*)&b1s[c*32 + qj*4];
    f32x4 bv1 = *(const f32x4*)&b1s[c*32 + 16 + qj*4];
    s16x8 pb0, pb1;
    {
      f32x4 h0 = hacc[0][0], h1 = hacc[1][0];
      h0.x = fmaxf(h0.x + bv0.x, 0.f); h0.y = fmaxf(h0.y + bv0.y, 0.f);
      h0.z = fmaxf(h0.z + bv0.z, 0.f); h0.w = fmaxf(h0.w + bv0.w, 0.f);
      h1.x = fmaxf(h1.x + bv1.x, 0.f); h1.y = fmaxf(h1.y + bv1.y, 0.f);
      h1.z = fmaxf(h1.z + bv1.z, 0.f); h1.w = fmaxf(h1.w + bv1.w, 0.f);
      u32x4 pw;
      pw.x = cvtpk(h0.x, h0.y); pw.y = cvtpk(h0.z, h0.w);
      pw.z = cvtpk(h1.x, h1.y); pw.w = cvtpk(h1.z, h1.w);
      pb0 = __builtin_bit_cast(s16x8, pw);
    }
    {
      f32x4 h0 = hacc[0][1], h1 = hacc[1][1];
      h0.x = fmaxf(h0.x + bv0.x, 0.f); h0.y = fmaxf(h0.y + bv0.y, 0.f);
      h0.z = fmaxf(h0.z + bv0.z, 0.f); h0.w = fmaxf(h0.w + bv0.w, 0.f);
      h1.x = fmaxf(h1.x + bv1.x, 0.f); h1.y = fmaxf(h1.y + bv1.y, 0.f);
      h1.z = fmaxf(h1.z + bv1.z, 0.f); h1.w = fmaxf(h1.w + bv1.w, 0.f);
      u32x4 pw;
      pw.x = cvtpk(h0.x, h0.y); pw.y = cvtpk(h0.z, h0.w);
      pw.z = cvtpk(h1.x, h1.y); pw.w = cvtpk(h1.z, h1.w);
      pb1 = __builtin_bit_cast(s16x8, pw);
    }

    // ---- phase 2: y += W2p(c) h  (VGPR-streamed W2, 4-deep prefetch) ----
    __builtin_amdgcn_s_setprio(1);
#pragma unroll
    for (int m = 0; m < 16; m += 4){
      s16x8 f0 = wfa, f1 = wfb, f2 = wfc, f3 = wfd;
      if (m + 4 < 16){
        wfa = w2c[(m + 4) * 64]; wfb = w2c[(m + 5) * 64];
        wfc = w2c[(m + 6) * 64]; wfd = w2c[(m + 7) * 64];
      }
      yacc[m+0][0] = MFMA(f0, pb0, yacc[m+0][0], 0, 0, 0);
      yacc[m+0][1] = MFMA(f0, pb1, yacc[m+0][1], 0, 0, 0);
      yacc[m+1][0] = MFMA(f1, pb0, yacc[m+1][0], 0, 0, 0);
      yacc[m+1][1] = MFMA(f1, pb1, yacc[m+1][1], 0, 0, 0);
      yacc[m+2][0] = MFMA(f2, pb0, yacc[m+2][0], 0, 0, 0);
      yacc[m+2][1] = MFMA(f2, pb1, yacc[m+2][1], 0, 0, 0);
      yacc[m+3][0] = MFMA(f3, pb0, yacc[m+3][0], 0, 0, 0);
      yacc[m+3][1] = MFMA(f3, pb1, yacc[m+3][1], 0, 0, 0);
    }
    __builtin_amdgcn_s_setprio(0);

    // one barrier per chunk: W1(c+1) staged (own 4 loads are the only
    // outstanding VMEM here; W2 reg-loads already consumed) + buffer reuse safe
    asm volatile("s_waitcnt vmcnt(0)" ::: "memory");
    __builtin_amdgcn_s_barrier();
    buf ^= 1;
  }

  // ---- store: yslot[2*tok+which][d] = bf16(y), packed b32, no atomics ----
#pragma unroll
  for (int ti = 0; ti < 2; ++ti){
    int ent = sTok[wave*32 + ti*16 + mrow];
    if (ent < 0) continue;
    int slot = ((ent & 0xFFFF) << 1) | ((ent >> 16) & 1);
    unsigned short* dst = yslot + (size_t)slot * 256;
#pragma unroll
    for (int m = 0; m < 16; ++m){
      unsigned lo = cvtpk(yacc[m][ti][0], yacc[m][ti][1]);
      unsigned hi = cvtpk(yacc[m][ti][2], yacc[m][ti][3]);
      *(unsigned*)(dst + m*16 + qj*4)     = lo;   // d = m*16 + qj*4 + {0,1}
      *(unsigned*)(dst + m*16 + qj*4 + 2) = hi;   // d = ... + {2,3}
    }
  }
}

// ---- combine: out[t] = p0*(y0+b2[e0]) + p1*(y1+b2[e1]); in-place over slots ----
__global__ __launch_bounds__(256) void combine_kernel(
    const float* __restrict__ rrec, const float* __restrict__ b2,
    float* __restrict__ out)
{
  int t = blockIdx.x * 4 + (threadIdx.x >> 6);
  int lane = threadIdx.x & 63;
  f32x4 rr = *(const f32x4*)(rrec + (size_t)t * 4);
  float p0 = rr.x, p1 = rr.y;
  int e0 = (int)rr.z, e1 = (int)rr.w;
  const u16x4* s0 = (const u16x4*)((const unsigned short*)out + (size_t)t * 512);
  u16x4 a = s0[lane];        // slot 2t   : cols lane*4..+3
  u16x4 b = s0[64 + lane];   // slot 2t+1
  f32x4 z0 = *(const f32x4*)(b2 + e0*D_DIM + 4*lane);
  f32x4 z1 = *(const f32x4*)(b2 + e1*D_DIM + 4*lane);
  f32x4 o;
  o.x = p0*(bf2f(a.x) + z0.x) + p1*(bf2f(b.x) + z1.x);
  o.y = p0*(bf2f(a.y) + z0.y) + p1*(bf2f(b.y) + z1.y);
  o.z = p0*(bf2f(a.z) + z0.z) + p1*(bf2f(b.z) + z1.z);
  o.w = p0*(bf2f(a.w) + z0.w) + p1*(bf2f(b.w) + z1.w);
  *(f32x4*)(out + (size_t)t * D_DIM + 4*lane) = o;
}

extern "C" void kernel_launch(void* const* d_in, const int* in_sizes, int n_in,
                              void* d_out, int out_size, void* d_ws, size_t ws_size,
                              hipStream_t stream) {
  const float* x  = (const float*)d_in[0];
  const float* Wg = (const float*)d_in[1];
  const float* bg = (const float*)d_in[2];
  const float* W1 = (const float*)d_in[3];
  const float* b1 = (const float*)d_in[4];
  const float* W2 = (const float*)d_in[5];
  const float* b2 = (const float*)d_in[6];
  float* out = (float*)d_out;
  char* ws = (char*)d_ws;

  char*  wsw     = ws;                        // 8,388,608 B converted weights
  int*   counts  = (int*)  (ws + 8388608);    // 512 B (8 x 64B lines)
  int*   tok_ids = (int*)  (ws + 8389632);    // 2,097,152 B
  float* rrec    = (float*)(ws + 10486784);   // 1,048,576 B (f32x4 per token)

  hipMemsetAsync(counts, 0, 512, stream);
  gate_kernel<<<T_TOKENS/GTB, 256, 0, stream>>>(x, Wg, bg, W1, W2, wsw,
                                                counts, tok_ids, rrec);
  ffn_kernel<<<E_NUM * (T_TOKENS/MT), 256, 0, stream>>>(x, wsw, b1, counts, tok_ids,
                                                        (unsigned short*)d_out);
  combine_kernel<<<T_TOKENS/4, 256, 0, stream>>>(rrec, b2, out);
}

// Round 9
// 260.303 us; speedup vs baseline: 4.0634x; 1.5700x over previous
//
#include <hip/hip_runtime.h>
#include <hip/hip_bf16.h>

#define T_TOKENS 65536
#define D_DIM 256
#define H_DIM 1024
#define E_NUM 8
#define MT 128
#define HC 32
#define NCHUNK 32              // H_DIM / HC
#define GTB 64                 // gate tokens per block

typedef __attribute__((ext_vector_type(4))) float f32x4;
typedef __attribute__((ext_vector_type(8))) short s16x8;
typedef __attribute__((ext_vector_type(4))) unsigned int u32x4;
typedef __attribute__((ext_vector_type(4))) unsigned short u16x4;
typedef __attribute__((address_space(3))) unsigned int lds_u32;
typedef const __attribute__((address_space(1))) unsigned int glb_u32;

#define MFMA __builtin_amdgcn_mfma_f32_16x16x32_bf16

__device__ __forceinline__ unsigned short f2bf(float f){
  union { float f; unsigned u; } v; v.f = f;
  unsigned r = v.u + 0x7FFFu + ((v.u >> 16) & 1u);
  return (unsigned short)(r >> 16);
}
__device__ __forceinline__ float bf2f(unsigned short h){
  return __uint_as_float((unsigned)h << 16);
}
__device__ __forceinline__ unsigned cvtpk(float lo, float hi){
  unsigned r;
  asm("v_cvt_pk_bf16_f32 %0, %1, %2" : "=v"(r) : "v"(lo), "v"(hi));
  return r;
}
__device__ __forceinline__ unsigned long long pack4(f32x4 v){
  return (unsigned long long)f2bf(v.x)
       | ((unsigned long long)f2bf(v.y) << 16)
       | ((unsigned long long)f2bf(v.z) << 32)
       | ((unsigned long long)f2bf(v.w) << 48);
}

// one 4-float unit of weight conversion into the swizzled chunk image (R5 layout).
// chunk(e,c) = 32KB: [W1c: 32 h-rows x 256 d, row 512B, swz ^((r&7)<<4)]
//  + [W2p at +16384: 256 d-rows x 32 h-slots, row 64B, slot s=qj*8+mi*4+j
//     holding W2[d][mi*16+qj*4+j], swz ^(((d>>1)&3)<<4)]
__device__ __forceinline__ void cvt_unit(int i, const float* __restrict__ W1,
                                         const float* __restrict__ W2,
                                         char* __restrict__ wsw){
  const int N1 = (E_NUM * H_DIM * D_DIM) / 4;      // 524288
  unsigned long long pk;
  size_t off;
  if (i < N1){
    pk = pack4(((const f32x4*)W1)[i]);
    int idx = i << 2;
    int e  = idx >> 18;
    int h  = (idx >> 8) & (H_DIM - 1);
    int d0 = idx & (D_DIM - 1);
    int c = h >> 5, r = h & 31;
    off = ((size_t)(e * NCHUNK + c) << 15)
        + (size_t)(((r << 9) + (d0 << 1)) ^ ((r & 7) << 4));
  } else {
    pk = pack4(((const f32x4*)W2)[i - N1]);
    int idx = (i - N1) << 2;
    int e  = idx >> 18;
    int d  = (idx >> 10) & (D_DIM - 1);
    int h0 = idx & (H_DIM - 1);
    int c  = h0 >> 5;
    int mi = (h0 >> 4) & 1, qjs = (h0 >> 2) & 3;
    int s2 = qjs * 16 + mi * 8;                    // byte offset of the 8B slot group
    off = ((size_t)(e * NCHUNK + c) << 15) + 16384
        + (size_t)((d << 6) + (s2 ^ (((d >> 1) & 3) << 4)));
  }
  *(unsigned long long*)(wsw + off) = pk;
}

// ---- gate (+fused weight conversion): scores, top-2, softmax, routing ----
__global__ __launch_bounds__(256) void gate_kernel(
    const float* __restrict__ x, const float* __restrict__ Wg,
    const float* __restrict__ bg,
    const float* __restrict__ W1, const float* __restrict__ W2,
    char* __restrict__ wsw,
    int* __restrict__ counts, int* __restrict__ tok_ids, float* __restrict__ rrec)
{
  __shared__ int lcnt[E_NUM];
  __shared__ int lbase[E_NUM];
  __shared__ unsigned char aexp[GTB * 2];
  __shared__ short         apos[GTB * 2];

  int tid = threadIdx.x, wave = tid >> 6, lane = tid & 63;

  // fused weight conversion: 4 units per thread
  int gthr = blockIdx.x * 256 + tid;
#pragma unroll
  for (int j = 0; j < 4; ++j)
    cvt_unit(gthr + j * ((T_TOKENS / GTB) * 256), W1, W2, wsw);

  if (tid < E_NUM) lcnt[tid] = 0;
  __syncthreads();

  int t0 = blockIdx.x * GTB;
#pragma unroll 1
  for (int i = 0; i < GTB / 4; ++i){
    int tl = wave * (GTB / 4) + i;
    int t = t0 + tl;
    f32x4 xv = *(const f32x4*)(x + (size_t)t * D_DIM + 4*lane);
    float s[E_NUM];
#pragma unroll
    for (int e = 0; e < E_NUM; ++e){
      f32x4 w = *(const f32x4*)(Wg + e*D_DIM + 4*lane);
      s[e] = xv.x*w.x + xv.y*w.y + xv.z*w.z + xv.w*w.w;
    }
#pragma unroll
    for (int off = 32; off; off >>= 1){
#pragma unroll
      for (int e = 0; e < E_NUM; ++e) s[e] += __shfl_xor(s[e], off);
    }
#pragma unroll
    for (int e = 0; e < E_NUM; ++e) s[e] += bg[e];
    int e0 = 0; float v0 = s[0];
#pragma unroll
    for (int e = 1; e < E_NUM; ++e) if (s[e] > v0){ v0 = s[e]; e0 = e; }
    int e1 = -1; float v1 = -3.4e38f;
#pragma unroll
    for (int e = 0; e < E_NUM; ++e){
      if (e == e0) continue;
      if (s[e] > v1){ v1 = s[e]; e1 = e; }
    }
    float ex = __expf(v1 - v0);
    float inv = 1.f / (1.f + ex);
    float p0 = inv, p1 = ex * inv;
    if (lane == 0){
      int li = tl * 2;
      int pos0 = atomicAdd(&lcnt[e0], 1);
      int pos1 = atomicAdd(&lcnt[e1], 1);
      aexp[li]   = (unsigned char)e0; apos[li]   = (short)pos0;
      aexp[li+1] = (unsigned char)e1; apos[li+1] = (short)pos1;
      f32x4 rr; rr.x = p0; rr.y = p1; rr.z = (float)e0; rr.w = (float)e1;
      *(f32x4*)(rrec + (size_t)t * 4) = rr;
    }
  }
  __syncthreads();
  if (tid < E_NUM) lbase[tid] = atomicAdd(counts + tid*16, lcnt[tid]);
  __syncthreads();
  if (tid < GTB * 2){
    int t = t0 + (tid >> 1);
    int e = aexp[tid];
    int idx = lbase[e] + apos[tid];
    tok_ids[e*T_TOKENS + idx] = t | ((tid & 1) << 16);   // token | which-bit
  }
}

// ---- grouped FFN, cross-chunk pipelined: iter c overlaps phase2(c) with
//      phase1(c+1). W1 = 4 x 8KB half-chunk ring (staged 2 chunks ahead),
//      W2 = 2 x 16KB dbuf. One vmcnt(0)+lgkmcnt(0)+barrier per chunk. ----
__global__ __launch_bounds__(256, 2) void ffn_kernel(
  const float* __restrict__ x, const char* __restrict__ wsw,
  const float* __restrict__ b1,
  const int* __restrict__ counts, const int* __restrict__ tok_ids,
  unsigned short* __restrict__ yslot)
{
  const int e    = blockIdx.x & 7;           // expert -> XCD pinning
  const int tile = blockIdx.x >> 3;
  const int cnt  = counts[e * 16];
  const int base = tile * MT;
  if (base >= cnt) return;

  __shared__ __align__(1024) unsigned short W1r[4][4096];   // 4 x 8KB ring
  __shared__ __align__(1024) unsigned short W2b[2][8192];   // 2 x 16KB dbuf
  __shared__ __align__(16)   float b1s[H_DIM];              // 4KB
  __shared__ int sTok[MT];                                  // 512B

  const int tid = threadIdx.x, wave = tid >> 6, lane = tid & 63;
  const int mrow = lane & 15, qj = lane >> 4;
  const char* wexp = wsw + ((size_t)(e * NCHUNK) << 15);

  // half-chunk j (=2c+mi): 8KB of W1, 2 loads/wave, ring slot j&3
  auto stage_w1h = [&](int j){
    const char* src = wexp + ((size_t)(j >> 1) << 15) + ((size_t)(j & 1) << 13);
    char* dst = (char*)&W1r[j & 3][0];
#pragma unroll
    for (int i = 0; i < 2; ++i){
      int ub = i * 4096 + wave * 1024;
      __builtin_amdgcn_global_load_lds(
        (glb_u32*)(src + ub + lane * 16),
        (lds_u32*)(dst + ub), 16, 0, 0);
    }
  };
  auto stage_w2 = [&](int c){
    const char* src = wexp + ((size_t)c << 15) + 16384;
    char* dst = (char*)&W2b[c & 1][0];
#pragma unroll
    for (int i = 0; i < 4; ++i){
      int ub = i * 4096 + wave * 1024;
      __builtin_amdgcn_global_load_lds(
        (glb_u32*)(src + ub + lane * 16),
        (lds_u32*)(dst + ub), 16, 0, 0);
    }
  };

  if (tid < MT){
    int idx = base + tid;
    sTok[tid] = (idx < cnt) ? tok_ids[e*T_TOKENS + idx] : -1;
  }
  *(f32x4*)&b1s[tid * 4] = ((const f32x4*)(b1 + e*H_DIM))[tid];
  __syncthreads();

  // gather x B-fragments into registers (32 tokens/wave, full D)
  s16x8 afr[2][8];
#pragma unroll
  for (int ti = 0; ti < 2; ++ti){
    int ent = sTok[wave*32 + ti*16 + mrow];
    int tk = ent & 0xFFFF;
    const f32x4* src = (const f32x4*)(x + (size_t)(ent < 0 ? 0 : tk) * D_DIM);
#pragma unroll
    for (int k = 0; k < 8; ++k){
      f32x4 a = src[k*8 + qj*2];
      f32x4 b = src[k*8 + qj*2 + 1];
      s16x8 f;
      f[0]=(short)f2bf(a.x); f[1]=(short)f2bf(a.y); f[2]=(short)f2bf(a.z); f[3]=(short)f2bf(a.w);
      f[4]=(short)f2bf(b.x); f[5]=(short)f2bf(b.y); f[6]=(short)f2bf(b.z); f[7]=(short)f2bf(b.w);
      if (ent < 0) f = (s16x8)(short)0;
      afr[ti][k] = f;
    }
  }

  // per-lane LDS byte bases (lane-constant swizzles)
  const int w1base = mrow*512 + ((qj*16) ^ ((mrow & 3) << 4)); // + ((ks^sb)<<6) within 8KB half
  const int w1sb   = (mrow >> 2) & 1;
  const int w2base = mrow*64 + ((qj*16) ^ (((mrow >> 1) & 3) << 4)); // + m*1024 within 16KB buf

  // prologue staging: W1 halves 0..3 (chunks 0,1) + W2(0)
  stage_w1h(0); stage_w1h(1); stage_w1h(2); stage_w1h(3);
  stage_w2(0);
  asm volatile("s_waitcnt vmcnt(0) lgkmcnt(0)" ::: "memory");
  __builtin_amdgcn_s_barrier();

  // prologue compute: hacc(0) from halves 0,1
  f32x4 hacc[2][2];
  hacc[0][0] = (f32x4){0.f,0.f,0.f,0.f}; hacc[0][1] = (f32x4){0.f,0.f,0.f,0.f};
  hacc[1][0] = (f32x4){0.f,0.f,0.f,0.f}; hacc[1][1] = (f32x4){0.f,0.f,0.f,0.f};
  {
    const char* Ha = (const char*)&W1r[0][0];
    const char* Hb = (const char*)&W1r[1][0];
#pragma unroll
    for (int ks = 0; ks < 8; ++ks){
      int ko = ((ks ^ w1sb) << 6);
      s16x8 wa = *(const s16x8*)(Ha + w1base + ko);
      s16x8 wb = *(const s16x8*)(Hb + w1base + ko);
      hacc[0][0] = MFMA(wa, afr[0][ks], hacc[0][0], 0, 0, 0);
      hacc[0][1] = MFMA(wa, afr[1][ks], hacc[0][1], 0, 0, 0);
      hacc[1][0] = MFMA(wb, afr[0][ks], hacc[1][0], 0, 0, 0);
      hacc[1][1] = MFMA(wb, afr[1][ks], hacc[1][1], 0, 0, 0);
    }
  }
  // all waves done reading rings 0,1 before iter 0 stages into them
  asm volatile("s_waitcnt lgkmcnt(0)" ::: "memory");
  __builtin_amdgcn_s_barrier();

  f32x4 yacc[16][2];
#pragma unroll
  for (int m = 0; m < 16; ++m){
    yacc[m][0] = (f32x4){0.f,0.f,0.f,0.f};
    yacc[m][1] = (f32x4){0.f,0.f,0.f,0.f};
  }

#pragma unroll 1
  for (int c = 0; c < NCHUNK; ++c){
    // issue staging first: W1 halves of chunk c+2 (rings (2c)&3,(2c+1)&3 —
    // read last iter), W2(c+1) (buf (c+1)&1 — read last iter)
    if (c < NCHUNK - 2){ stage_w1h(2*c + 4); stage_w1h(2*c + 5); }
    if (c < NCHUNK - 1){ stage_w2(c + 1); }

    __builtin_amdgcn_s_setprio(1);

    // ---- pack hacc(c): bias + relu + bf16 B-fragments ----
    f32x4 bv0 = *(const f32x4*)&b1s[c*32 + qj*4];
    f32x4 bv1 = *(const f32x4*)&b1s[c*32 + 16 + qj*4];
    s16x8 pb0, pb1;
    {
      f32x4 h0 = hacc[0][0], h1 = hacc[1][0];
      h0.x = fmaxf(h0.x + bv0.x, 0.f); h0.y = fmaxf(h0.y + bv0.y, 0.f);
      h0.z = fmaxf(h0.z + bv0.z, 0.f); h0.w = fmaxf(h0.w + bv0.w, 0.f);
      h1.x = fmaxf(h1.x + bv1.x, 0.f); h1.y = fmaxf(h1.y + bv1.y, 0.f);
      h1.z = fmaxf(h1.z + bv1.z, 0.f); h1.w = fmaxf(h1.w + bv1.w, 0.f);
      u32x4 pw;
      pw.x = cvtpk(h0.x, h0.y); pw.y = cvtpk(h0.z, h0.w);
      pw.z = cvtpk(h1.x, h1.y); pw.w = cvtpk(h1.z, h1.w);
      pb0 = __builtin_bit_cast(s16x8, pw);
    }
    {
      f32x4 h0 = hacc[0][1], h1 = hacc[1][1];
      h0.x = fmaxf(h0.x + bv0.x, 0.f); h0.y = fmaxf(h0.y + bv0.y, 0.f);
      h0.z = fmaxf(h0.z + bv0.z, 0.f); h0.w = fmaxf(h0.w + bv0.w, 0.f);
      h1.x = fmaxf(h1.x + bv1.x, 0.f); h1.y = fmaxf(h1.y + bv1.y, 0.f);
      h1.z = fmaxf(h1.z + bv1.z, 0.f); h1.w = fmaxf(h1.w + bv1.w, 0.f);
      u32x4 pw;
      pw.x = cvtpk(h0.x, h0.y); pw.y = cvtpk(h0.z, h0.w);
      pw.z = cvtpk(h1.x, h1.y); pw.w = cvtpk(h1.z, h1.w);
      pb1 = __builtin_bit_cast(s16x8, pw);
    }

    // re-zero hacc for chunk c+1 (built below, interleaved with phase 2)
    f32x4 ha00 = (f32x4){0.f,0.f,0.f,0.f}, ha01 = (f32x4){0.f,0.f,0.f,0.f};
    f32x4 ha10 = (f32x4){0.f,0.f,0.f,0.f}, ha11 = (f32x4){0.f,0.f,0.f,0.f};

    // ---- phase 2(c) [reads W2b[c&1]]  ∥  phase 1(c+1) [reads rings 2c+2,2c+3]
    //      — independent streams; scheduler interleaves ----
    const char* W2c = (const char*)&W2b[c & 1][0];
#pragma unroll
    for (int m = 0; m < 16; ++m){
      s16x8 w2f = *(const s16x8*)(W2c + w2base + m*1024);
      yacc[m][0] = MFMA(w2f, pb0, yacc[m][0], 0, 0, 0);
      yacc[m][1] = MFMA(w2f, pb1, yacc[m][1], 0, 0, 0);
      if ((m & 1) == 0 && c < NCHUNK - 1){
        int ks = m >> 1;
        int ko = ((ks ^ w1sb) << 6);
        const char* Ha = (const char*)&W1r[(2*c + 2) & 3][0];
        const char* Hb = (const char*)&W1r[(2*c + 3) & 3][0];
        s16x8 wa = *(const s16x8*)(Ha + w1base + ko);
        s16x8 wb = *(const s16x8*)(Hb + w1base + ko);
        ha00 = MFMA(wa, afr[0][ks], ha00, 0, 0, 0);
        ha01 = MFMA(wa, afr[1][ks], ha01, 0, 0, 0);
        ha10 = MFMA(wb, afr[0][ks], ha10, 0, 0, 0);
        ha11 = MFMA(wb, afr[1][ks], ha11, 0, 0, 0);
      }
    }
    hacc[0][0] = ha00; hacc[0][1] = ha01;
    hacc[1][0] = ha10; hacc[1][1] = ha11;

    __builtin_amdgcn_s_setprio(0);

    // single sync point: staged loads (issued at iter top) landed; all waves'
    // LDS reads retired -> rings/bufs safe to overwrite next iter
    asm volatile("s_waitcnt vmcnt(0) lgkmcnt(0)" ::: "memory");
    __builtin_amdgcn_s_barrier();
  }

  // ---- store: yslot[2*tok+which][d] = bf16(y), packed b32, no atomics ----
#pragma unroll
  for (int ti = 0; ti < 2; ++ti){
    int ent = sTok[wave*32 + ti*16 + mrow];
    if (ent < 0) continue;
    int slot = ((ent & 0xFFFF) << 1) | ((ent >> 16) & 1);
    unsigned short* dst = yslot + (size_t)slot * 256;
#pragma unroll
    for (int m = 0; m < 16; ++m){
      unsigned lo = cvtpk(yacc[m][ti][0], yacc[m][ti][1]);
      unsigned hi = cvtpk(yacc[m][ti][2], yacc[m][ti][3]);
      *(unsigned*)(dst + m*16 + qj*4)     = lo;   // d = m*16 + qj*4 + {0,1}
      *(unsigned*)(dst + m*16 + qj*4 + 2) = hi;   // d = ... + {2,3}
    }
  }
}

// ---- combine: out[t] = p0*(y0+b2[e0]) + p1*(y1+b2[e1]); in-place over slots ----
__global__ __launch_bounds__(256) void combine_kernel(
    const float* __restrict__ rrec, const float* __restrict__ b2,
    float* __restrict__ out)
{
  int t = blockIdx.x * 4 + (threadIdx.x >> 6);
  int lane = threadIdx.x & 63;
  f32x4 rr = *(const f32x4*)(rrec + (size_t)t * 4);
  float p0 = rr.x, p1 = rr.y;
  int e0 = (int)rr.z, e1 = (int)rr.w;
  const u16x4* s0 = (const u16x4*)((const unsigned short*)out + (size_t)t * 512);
  u16x4 a = s0[lane];        // slot 2t   : cols lane*4..+3
  u16x4 b = s0[64 + lane];   // slot 2t+1
  f32x4 z0 = *(const f32x4*)(b2 + e0*D_DIM + 4*lane);
  f32x4 z1 = *(const f32x4*)(b2 + e1*D_DIM + 4*lane);
  f32x4 o;
  o.x = p0*(bf2f(a.x) + z0.x) + p1*(bf2f(b.x) + z1.x);
  o.y = p0*(bf2f(a.y) + z0.y) + p1*(bf2f(b.y) + z1.y);
  o.z = p0*(bf2f(a.z) + z0.z) + p1*(bf2f(b.z) + z1.z);
  o.w = p0*(bf2f(a.w) + z0.w) + p1*(bf2f(b.w) + z1.w);
  *(f32x4*)(out + (size_t)t * D_DIM + 4*lane) = o;
}

extern "C" void kernel_launch(void* const* d_in, const int* in_sizes, int n_in,
                              void* d_out, int out_size, void* d_ws, size_t ws_size,
                              hipStream_t stream) {
  const float* x  = (const float*)d_in[0];
  const float* Wg = (const float*)d_in[1];
  const float* bg = (const float*)d_in[2];
  const float* W1 = (const float*)d_in[3];
  const float* b1 = (const float*)d_in[4];
  const float* W2 = (const float*)d_in[5];
  const float* b2 = (const float*)d_in[6];
  float* out = (float*)d_out;
  char* ws = (char*)d_ws;

  char*  wsw     = ws;                        // 8,388,608 B swizzled weights
  int*   counts  = (int*)  (ws + 8388608);    // 512 B (8 x 64B lines)
  int*   tok_ids = (int*)  (ws + 8389632);    // 2,097,152 B
  float* rrec    = (float*)(ws + 10486784);   // 1,048,576 B (f32x4 per token)

  hipMemsetAsync(counts, 0, 512, stream);
  gate_kernel<<<T_TOKENS/GTB, 256, 0, stream>>>(x, Wg, bg, W1, W2, wsw,
                                                counts, tok_ids, rrec);
  ffn_kernel<<<E_NUM * (T_TOKENS/MT), 256, 0, stream>>>(x, wsw, b1, counts, tok_ids,
                                                        (unsigned short*)d_out);
  combine_kernel<<<T_TOKENS/4, 256, 0, stream>>>(rrec, b2, out);
}